// Round 11
// baseline (175.847 us; speedup 1.0000x reference)
//
#include <hip/hip_runtime.h>

#define NBINS 4096
#define B 4
#define C 16
#define HID 32
#define NI 32
#define INTER 36864           // 192*192 interior pixels per image
#define PADMULT 28672         // 256*256 - 192*192 padded pixels per instance
#define EPSF 1e-6f
#define THR 256
#define BPI 144               // blocks per image, 1 pixel/thread
#define NBLK (B * BPI)        // 576 free-running blocks

// ---- ws layout (uint units). NOTHING needs pre-zeroing: every word is
// plain-stored before it is read (k_init eliminated).
#define OFF_PCNT  0                         // [NBLK][NI] float (block partials)
#define OFF_PSUM  (OFF_PCNT + NBLK*NI)      // [NBLK][NI*C] float
#define OFF_PMK   (OFF_PSUM + NBLK*NI*C)    // [NBLK] float: block max ||e||^2
#define OFF_V     (OFF_PMK + NBLK)          // [B][NI*HID] float (8B aligned)
#define OFF_PERR  (OFF_V + B*NI*HID)        // [B][NI] float
#define OFF_RANGE (OFF_PERR + B*NI)         // [B][2] float: emin, emax
#define OFF_HCNT  320000                    // [NBLK][NBINS] packed cnt|pos<<16
#define OFF_FCNT  (OFF_HCNT + NBLK*NBINS)   // [B][NBINS]
#define OFF_FPOS  (OFF_FCNT + B*NBINS)      // [B][NBINS]

#if defined(__has_builtin)
#if __has_builtin(__builtin_elementwise_fma) && __has_builtin(__builtin_elementwise_max)
#define USE_PK 1
#endif
#endif

typedef float v2f __attribute__((ext_vector_type(2)));

__device__ inline unsigned fmap(float f) {
    unsigned u = __float_as_uint(f);
    return (u & 0x80000000u) ? ~u : (u | 0x80000000u);
}
__device__ inline float funmap(unsigned k) {
    return (k & 0x80000000u) ? __uint_as_float(k & 0x7fffffffu)
                             : __uint_as_float(~k);
}

// k_stats: per-block partial counts / weighted embedding sums / max ||e||^2,
// flushed with PLAIN coalesced stores (no global atomics, no init kernel).
__global__ __launch_bounds__(THR, 4) void k_stats(
        const float* __restrict__ emb, const float* __restrict__ wgt,
        const int* __restrict__ gt, float* ws) {
    __shared__ float s_cnt[NI];
    __shared__ float s_sum[NI * 17];   // stride 17: avoid 2-bank aliasing
    __shared__ unsigned s_mk;
    int tid = threadIdx.x, bx = blockIdx.x;
    int img = bx / BPI;
    int q = (bx - img * BPI) * THR + tid;
    for (int i = tid; i < NI; i += THR) s_cnt[i] = 0.f;
    for (int i = tid; i < NI * 17; i += THR) s_sum[i] = 0.f;
    if (tid == 0) s_mk = 0u;
    __syncthreads();

    int g = gt[img * INTER + q];
    const float* ep = emb + (size_t)img * C * INTER + q;
    float e[C];
    float nrm = 0.f;
    #pragma unroll
    for (int c = 0; c < C; c++) { e[c] = ep[c * INTER]; nrm = fmaf(e[c], e[c], nrm); }
    if (g > 0) {
        float wv = wgt[img * INTER + q];
        atomicAdd(&s_cnt[g - 1], wv);
        #pragma unroll
        for (int c = 0; c < C; c++)
            atomicAdd(&s_sum[(g - 1) * 17 + c], e[c] * wv);
    }
    atomicMax(&s_mk, fmap(nrm));
    __syncthreads();
    for (int i = tid; i < NI; i += THR)
        ws[OFF_PCNT + bx * NI + i] = s_cnt[i];
    for (int i = tid; i < NI * C; i += THR) {
        int n = i / C, c = i - n * C;
        ws[OFF_PSUM + bx * (NI * C) + i] = s_sum[n * 17 + c];
    }
    if (tid == 0) ws[OFF_PMK + bx] = funmap(s_mk);
}

// k_centers: one block per image. Reduce the BPI partials, compute
// v[n,k] = centers.W1 + b1, pad errors (u=0 exact), and the analytic
// histogram range via Cauchy-Schwarz: |u_k| <= max||e|| * ||W1_k||.
__global__ void k_centers(const float* __restrict__ W1, const float* __restrict__ b1,
                          const float* __restrict__ W2, const float* __restrict__ b2,
                          float* ws, unsigned* wsu) {
    int im = blockIdx.x, tid = threadIdx.x;
    __shared__ float s_cnt[NI];
    __shared__ float s_cs[NI * C];
    __shared__ float s_mx[THR];
    __shared__ float s_v[NI * HID];
    __shared__ float s_a[HID];
    __shared__ unsigned s_lo, s_hi;

    // reduce partials (coalesced: lanes read consecutive idx)
    for (int idx = tid; idx < NI * C; idx += THR) {
        float s = 0.f;
        for (int r = 0; r < BPI; r++)
            s += ws[OFF_PSUM + (size_t)(im * BPI + r) * (NI * C) + idx];
        s_cs[idx] = s;
    }
    if (tid < NI) {
        float s = 0.f;
        for (int r = 0; r < BPI; r++)
            s += ws[OFF_PCNT + (im * BPI + r) * NI + tid];
        s_cnt[tid] = s;
    }
    s_mx[tid] = (tid < BPI) ? ws[OFF_PMK + im * BPI + tid] : 0.f;
    if (tid == 0) { s_lo = 0xFFFFFFFFu; s_hi = 0u; }
    __syncthreads();
    for (int s = THR / 2; s > 0; s >>= 1) {
        if (tid < s) s_mx[tid] = fmaxf(s_mx[tid], s_mx[tid + s]);
        __syncthreads();
    }
    float M = sqrtf(s_mx[0]);
    if (tid < HID) {
        float ssq = 0.f;
        #pragma unroll
        for (int c = 0; c < C; c++)
            ssq = fmaf(W1[c * HID + tid], W1[c * HID + tid], ssq);
        s_a[tid] = M * sqrtf(ssq);
    }
    for (int idx = tid; idx < NI * HID; idx += THR) {
        int n = idx >> 5, k = idx & 31;
        float cv = s_cnt[n] + EPSF;
        float acc = b1[k];
        #pragma unroll
        for (int c = 0; c < C; c++)
            acc += (s_cs[n * C + c] / cv) * W1[c * HID + k];
        s_v[idx] = acc;
        ws[OFF_V + im * NI * HID + idx] = acc;
    }
    __syncthreads();
    float b2v = b2[0];
    if (tid < NI) {
        float lo = b2v, hi = b2v, lgp = b2v;
        #pragma unroll
        for (int k = 0; k < HID; k++) {
            float vk = s_v[tid * HID + k], a = s_a[k], w = W2[k];
            float thi = fmaxf(vk + a, 0.f), tlo = fmaxf(vk - a, 0.f);
            hi += w * (w > 0.f ? thi : tlo);
            lo += w * (w > 0.f ? tlo : thi);
            lgp = fmaf(fmaxf(vk, 0.f), w, lgp);   // pad pixels: u = 0 exact
        }
        float pe = 1.f + lgp;
        ws[OFF_PERR + im * NI + tid] = pe;
        atomicMin(&s_lo, fmap(fminf(1.f - hi, 1.f + lo)));
        atomicMax(&s_hi, fmap(fmaxf(1.f - lo, 1.f + hi)));
    }
    __syncthreads();
    if (tid == 0) {
        ((float*)wsu)[OFF_RANGE + im * 2]     = funmap(s_lo);
        ((float*)wsu)[OFF_RANGE + im * 2 + 1] = funmap(s_hi);
    }
}

// k_hist: LDS histogram per block, plain-store flush. Inner loop in PACKED
// fp32 (v_pk_fma_f32 / v_pk_max_f32): gfx950 FP32 peak (157 TF) is only
// reachable via VOP3P -- halves the 3*HID VALU inst per (pixel, instance).
__global__ __launch_bounds__(THR, 4) void k_hist(
        const float* __restrict__ emb, const int* __restrict__ gt,
        const float* __restrict__ W1, const float* __restrict__ W2,
        const float* __restrict__ b2, const float* __restrict__ ws,
        unsigned* wsu) {
    __shared__ unsigned s_h[NBINS];   // 16 KB
    int tid = threadIdx.x, bx = blockIdx.x;
    int img = bx / BPI;
    int q = (bx - img * BPI) * THR + tid;
    for (int i = tid; i < NBINS; i += THR) s_h[i] = 0u;
    float emin = ((const float*)wsu)[OFF_RANGE + img * 2];
    float emax = ((const float*)wsu)[OFF_RANGE + img * 2 + 1];
    float invbw = (float)NBINS / fmaxf(emax - emin, 1e-20f);
    float b2v = b2[0];
    const float* vimg = ws + OFF_V + img * NI * HID;   // wave-uniform
    __syncthreads();

    const float* ep = emb + (size_t)img * C * INTER + q;
    int g = gt[img * INTER + q];
#ifdef USE_PK
    const v2f* W12 = (const v2f*)W1;
    const v2f* W22 = (const v2f*)W2;
    const v2f z2 = {0.f, 0.f};
    v2f u2[HID / 2];
    #pragma unroll
    for (int j = 0; j < HID / 2; j++) u2[j] = z2;
    #pragma unroll
    for (int c = 0; c < C; c++) {
        float ev = ep[c * INTER];
        v2f ev2 = {ev, ev};
        #pragma unroll
        for (int j = 0; j < HID / 2; j++)
            u2[j] = __builtin_elementwise_fma(ev2, W12[c * (HID / 2) + j], u2[j]);
    }
    for (int n = 0; n < NI; n++) {
        const v2f* vn2 = (const v2f*)(vimg + n * HID);   // wave-uniform
        v2f a0 = z2, a1 = z2;
        #pragma unroll
        for (int j = 0; j < HID / 2; j += 2) {
            a0 = __builtin_elementwise_fma(
                     __builtin_elementwise_max(vn2[j] - u2[j], z2), W22[j], a0);
            a1 = __builtin_elementwise_fma(
                     __builtin_elementwise_max(vn2[j + 1] - u2[j + 1], z2), W22[j + 1], a1);
        }
        v2f a = a0 + a1;
        float lg = b2v + a.x + a.y;
        bool pos = (g == n + 1);
        float err = pos ? (1.f - lg) : (1.f + lg);
        int bn = (int)((emax - err) * invbw);
        bn = bn < 0 ? 0 : (bn >= NBINS ? NBINS - 1 : bn);
        atomicAdd(&s_h[bn], pos ? 0x10001u : 1u);
    }
#else
    float u[HID];
    #pragma unroll
    for (int k = 0; k < HID; k++) u[k] = 0.f;
    #pragma unroll
    for (int c = 0; c < C; c++) {
        float ev = ep[c * INTER];
        #pragma unroll
        for (int k = 0; k < HID; k++) u[k] = fmaf(ev, W1[c * HID + k], u[k]);
    }
    for (int n = 0; n < NI; n++) {
        const float* vn = vimg + n * HID;
        float lg0 = b2v, lg1 = 0.f, lg2 = 0.f, lg3 = 0.f;
        #pragma unroll
        for (int k = 0; k < HID; k += 4) {
            lg0 = fmaf(fmaxf(vn[k + 0] - u[k + 0], 0.f), W2[k + 0], lg0);
            lg1 = fmaf(fmaxf(vn[k + 1] - u[k + 1], 0.f), W2[k + 1], lg1);
            lg2 = fmaf(fmaxf(vn[k + 2] - u[k + 2], 0.f), W2[k + 2], lg2);
            lg3 = fmaf(fmaxf(vn[k + 3] - u[k + 3], 0.f), W2[k + 3], lg3);
        }
        float lg = (lg0 + lg1) + (lg2 + lg3);
        bool pos = (g == n + 1);
        float err = pos ? (1.f - lg) : (1.f + lg);
        int bn = (int)((emax - err) * invbw);
        bn = bn < 0 ? 0 : (bn >= NBINS ? NBINS - 1 : bn);
        atomicAdd(&s_h[bn], pos ? 0x10001u : 1u);
    }
#endif
    __syncthreads();
    unsigned* gc = wsu + OFF_HCNT + (size_t)bx * NBINS;
    for (int i = tid; i < NBINS; i += THR) gc[i] = s_h[i];
}

// k_reduce: collapse the BPI partials per (img, bin). 64 blocks, coalesced.
__global__ void k_reduce(unsigned* wsu) {
    int tid = threadIdx.x, b = blockIdx.x;
    int img = b >> 4;
    int bn = (b & 15) * 256 + tid;            // 16 blocks/image * 256 = 4096
    unsigned cnt = 0, pos = 0;
    for (int r = 0; r < BPI; r++) {
        unsigned pk = wsu[OFF_HCNT + (size_t)(img * BPI + r) * NBINS + bn];
        cnt += pk & 0xFFFFu;
        pos += pk >> 16;
    }
    wsu[OFF_FCNT + img * NBINS + bn] = cnt;
    wsu[OFF_FPOS + img * NBINS + bn] = pos;
}

// k_loss: ONE block loops the 4 images (Lovasz scan in double), accumulates,
// plain-stores out[0] -- no atomic, so no output zeroing dispatch needed.
__global__ void k_loss(const float* ws, const unsigned* wsu, float* out) {
    const int T = 256, CHUNK = NBINS / T;     // 16
    int tid = threadIdx.x;
    __shared__ unsigned s_cnt[NBINS], s_pos[NBINS];  // 32 KB
    __shared__ float s_sum[NBINS];                   // 16 KB
    __shared__ unsigned s_pc[T], s_pp[T];
    __shared__ double s_a[T];
    __shared__ double s_tot;
    if (tid == 0) s_tot = 0.0;

    for (int img = 0; img < B; ++img) {
        float emin = ((const float*)wsu)[OFF_RANGE + img * 2];
        float emax = ((const float*)wsu)[OFF_RANGE + img * 2 + 1];
        float bw = (emax - emin) / (float)NBINS;
        float invbw = (float)NBINS / fmaxf(emax - emin, 1e-20f);
        for (int i = tid; i < NBINS; i += T) {
            unsigned cv = wsu[OFF_FCNT + img * NBINS + i];
            s_cnt[i] = cv;
            s_pos[i] = wsu[OFF_FPOS + img * NBINS + i];
            float center = emax - ((float)i + 0.5f) * bw;
            s_sum[i] = (float)cv * fmaxf(center, 0.f);
        }
        __syncthreads();
        // pad-region: exact error values, PADMULT each, label 0
        if (tid < NI) {
            float pe = ws[OFF_PERR + img * NI + tid];
            int bn = (int)((emax - pe) * invbw);
            bn = bn < 0 ? 0 : (bn >= NBINS ? NBINS - 1 : bn);
            atomicAdd(&s_cnt[bn], (unsigned)PADMULT);
            atomicAdd(&s_sum[bn], (float)PADMULT * fmaxf(pe, 0.f));
        }
        __syncthreads();
        unsigned ccnt = 0, cpos = 0;
        for (int j = 0; j < CHUNK; j++) {
            int bn = tid * CHUNK + j;
            ccnt += s_cnt[bn]; cpos += s_pos[bn];
        }
        s_pc[tid] = ccnt; s_pp[tid] = cpos;
        __syncthreads();
        for (int off = 1; off < T; off <<= 1) {
            unsigned ac = 0, ap = 0;
            if (tid >= off) { ac = s_pc[tid - off]; ap = s_pp[tid - off]; }
            __syncthreads();
            s_pc[tid] += ac; s_pp[tid] += ap;
            __syncthreads();
        }
        double Gd = (double)s_pp[T - 1];
        double r = (double)(s_pc[tid] - ccnt);
        double L = (double)(s_pp[tid] - cpos);
        double Jprev = 1.0 - (Gd - L) / (Gd + r - L);
        double acc = 0.0;
        for (int j = 0; j < CHUNK; j++) {
            int bn = tid * CHUNK + j;
            unsigned cv = s_cnt[bn], pv = s_pos[bn];
            if (cv) {
                r += (double)cv; L += (double)pv;
                double J = 1.0 - (Gd - L) / (Gd + r - L);
                double mean = (double)s_sum[bn] / (double)cv;
                acc += mean * (J - Jprev);
                Jprev = J;
            }
        }
        s_a[tid] = acc;
        __syncthreads();
        for (int s = T / 2; s > 0; s >>= 1) {
            if (tid < s) s_a[tid] += s_a[tid + s];
            __syncthreads();
        }
        if (tid == 0) s_tot += s_a[0];
        __syncthreads();   // protect s_cnt/s_pos reuse next image
    }
    if (tid == 0) out[0] = (float)(s_tot * 0.25);   // mean over B=4
}

extern "C" void kernel_launch(void* const* d_in, const int* in_sizes, int n_in,
                              void* d_out, int out_size, void* d_ws, size_t ws_size,
                              hipStream_t stream) {
    const float* emb = (const float*)d_in[0];
    const float* wgt = (const float*)d_in[1];
    const int*   gt  = (const int*)d_in[2];
    const float* W1  = (const float*)d_in[3];
    const float* b1  = (const float*)d_in[4];
    const float* W2  = (const float*)d_in[5];
    const float* b2  = (const float*)d_in[6];
    float* out = (float*)d_out;
    float* ws  = (float*)d_ws;
    unsigned* wsu = (unsigned*)d_ws;

    k_stats<<<NBLK, THR, 0, stream>>>(emb, wgt, gt, ws);
    k_centers<<<B, THR, 0, stream>>>(W1, b1, W2, b2, ws, wsu);
    k_hist<<<NBLK, THR, 0, stream>>>(emb, gt, W1, W2, b2, ws, wsu);
    k_reduce<<<64, 256, 0, stream>>>(wsu);
    k_loss<<<1, 256, 0, stream>>>(ws, wsu, out);
}

// Round 12
// 140.516 us; speedup vs baseline: 1.2514x; 1.2514x over previous
//
#include <hip/hip_runtime.h>

#define NBINS 2048
#define B 4
#define C 16
#define HID 32
#define NI 32
#define INTER 36864           // 192*192 interior pixels per image
#define PADMULT 28672         // 256*256 - 192*192 padded pixels per instance
#define EPSF 1e-6f
#define THR 256
#define BPI 144               // blocks per image, 1 pixel/thread
#define NBLK (B * BPI)        // 576 free-running blocks

// ---- ws layout (uint units)  [R10-winner layout, NBINS=2048]
#define OFF_COUNTS 0                      // [B][NI] float
#define OFF_CSUMS  (OFF_COUNTS + B*NI)    // [B][NI][C] float
#define OFF_V      (OFF_CSUMS + B*NI*C)   // [B][NI][HID] float
#define OFF_PERR   (OFF_V + B*NI*HID)     // [B][NI] float
#define OFF_MKEY   (OFF_PERR + B*NI)      // [B] uint: fmap(max ||e||^2)
#define OFF_RANGE  (OFF_MKEY + B)         // [B][2] float: emin, emax
#define CTRL_END   (OFF_RANGE + 2*B)
#define OFF_HCNT   8192                   // [NBLK][NBINS] packed cnt|pos<<16
#define OFF_FCNT   (OFF_HCNT + NBLK*NBINS)  // [B][NBINS]
#define OFF_FPOS   (OFF_FCNT + B*NBINS)     // [B][NBINS]

__device__ inline unsigned fmap(float f) {
    unsigned u = __float_as_uint(f);
    return (u & 0x80000000u) ? ~u : (u | 0x80000000u);
}
__device__ inline float funmap(unsigned k) {
    return (k & 0x80000000u) ? __uint_as_float(k & 0x7fffffffu)
                             : __uint_as_float(~k);
}

// Tiny init: zero control region + out. Kernel boundaries provide all
// inter-kernel visibility (no fences anywhere -- R9 lesson).
__global__ void k_init(unsigned* wsu, float* out) {
    int i = threadIdx.x;
    if (i < CTRL_END) wsu[i] = 0u;
    if (i == 0) out[0] = 0.f;
}

// k_stats: per-instance counts & weighted embedding sums + max ||e||^2.
// LDS-local accumulation, then device-scope global atomics (coherent).
__global__ __launch_bounds__(THR, 4) void k_stats(
        const float* __restrict__ emb, const float* __restrict__ wgt,
        const int* __restrict__ gt, float* ws, unsigned* wsu) {
    __shared__ float s_cnt[NI];
    __shared__ float s_sum[NI * 17];   // stride 17: avoid 2-bank aliasing
    __shared__ unsigned s_mk;
    int tid = threadIdx.x, bx = blockIdx.x;
    int img = bx / BPI;
    int q = (bx - img * BPI) * THR + tid;
    for (int i = tid; i < NI; i += THR) s_cnt[i] = 0.f;
    for (int i = tid; i < NI * 17; i += THR) s_sum[i] = 0.f;
    if (tid == 0) s_mk = 0u;
    __syncthreads();

    int g = gt[img * INTER + q];
    const float* ep = emb + (size_t)img * C * INTER + q;
    float e[C];
    float nrm = 0.f;
    #pragma unroll
    for (int c = 0; c < C; c++) { e[c] = ep[c * INTER]; nrm = fmaf(e[c], e[c], nrm); }
    if (g > 0) {
        float wv = wgt[img * INTER + q];
        atomicAdd(&s_cnt[g - 1], wv);
        #pragma unroll
        for (int c = 0; c < C; c++)
            atomicAdd(&s_sum[(g - 1) * 17 + c], e[c] * wv);
    }
    atomicMax(&s_mk, fmap(nrm));
    __syncthreads();
    for (int i = tid; i < NI; i += THR)
        atomicAdd(&ws[OFF_COUNTS + img * NI + i], s_cnt[i]);
    for (int i = tid; i < NI * C; i += THR) {
        int n = i / C, c = i - n * C;
        atomicAdd(&ws[OFF_CSUMS + (img * NI + n) * C + c], s_sum[n * 17 + c]);
    }
    if (tid == 0) atomicMax(&wsu[OFF_MKEY + img], s_mk);
}

// k_centers: one block per image. v[n,k] = centers.W1 + b1; pad errors
// (u=0 exactly); analytic histogram range via Cauchy-Schwarz:
// |u_k| <= max||e|| * ||W1_k|| => lg in [lo,hi] per instance.
__global__ void k_centers(const float* __restrict__ W1, const float* __restrict__ b1,
                          const float* __restrict__ W2, const float* __restrict__ b2,
                          float* ws, unsigned* wsu) {
    int im = blockIdx.x, tid = threadIdx.x;
    __shared__ float s_v[NI * HID];
    __shared__ float s_a[HID];
    __shared__ unsigned s_lo, s_hi;
    float b2v = b2[0];
    float M = sqrtf(funmap(wsu[OFF_MKEY + im]));
    if (tid < HID) {
        float ssq = 0.f;
        #pragma unroll
        for (int c = 0; c < C; c++)
            ssq = fmaf(W1[c * HID + tid], W1[c * HID + tid], ssq);
        s_a[tid] = M * sqrtf(ssq);
    }
    if (tid == 0) { s_lo = 0xFFFFFFFFu; s_hi = 0u; }
    for (int idx = tid; idx < NI * HID; idx += THR) {
        int n = idx >> 5, k = idx & 31;
        float cv = ws[OFF_COUNTS + im * NI + n] + EPSF;
        float acc = b1[k];
        #pragma unroll
        for (int c = 0; c < C; c++)
            acc += (ws[OFF_CSUMS + (im * NI + n) * C + c] / cv) * W1[c * HID + k];
        s_v[idx] = acc;
        ws[OFF_V + im * NI * HID + idx] = acc;
    }
    __syncthreads();
    if (tid < NI) {
        float lo = b2v, hi = b2v, lgp = b2v;
        #pragma unroll
        for (int k = 0; k < HID; k++) {
            float vk = s_v[tid * HID + k], a = s_a[k], w = W2[k];
            float thi = fmaxf(vk + a, 0.f), tlo = fmaxf(vk - a, 0.f);
            hi += w * (w > 0.f ? thi : tlo);
            lo += w * (w > 0.f ? tlo : thi);
            lgp = fmaf(fmaxf(vk, 0.f), w, lgp);   // pad pixels: u = 0 exact
        }
        float pe = 1.f + lgp;
        ws[OFF_PERR + im * NI + tid] = pe;
        atomicMin(&s_lo, fmap(fminf(1.f - hi, 1.f + lo)));
        atomicMax(&s_hi, fmap(fmaxf(1.f - lo, 1.f + hi)));
    }
    __syncthreads();
    if (tid == 0) {
        ((float*)wsu)[OFF_RANGE + im * 2]     = funmap(s_lo);
        ((float*)wsu)[OFF_RANGE + im * 2 + 1] = funmap(s_hi);
    }
}

// k_hist: LDS histogram per block (free-running), plain-store flush.
// v/W1/W2 via wave-uniform scalar loads; SCALAR fp32 inner loop (the packed
// v2f variant regressed in R11: no v_pk_max_f32 on CDNA4, and the vector
// casts defeat SGPR-load recognition). Packed cnt|pos<<16 (<=8192/block).
__global__ __launch_bounds__(THR, 4) void k_hist(
        const float* __restrict__ emb, const int* __restrict__ gt,
        const float* __restrict__ W1, const float* __restrict__ W2,
        const float* __restrict__ b2, const float* __restrict__ ws,
        unsigned* wsu) {
    __shared__ unsigned s_h[NBINS];   // 8 KB
    int tid = threadIdx.x, bx = blockIdx.x;
    int img = bx / BPI;
    int q = (bx - img * BPI) * THR + tid;
    for (int i = tid; i < NBINS; i += THR) s_h[i] = 0u;
    float emin = ((const float*)wsu)[OFF_RANGE + img * 2];
    float emax = ((const float*)wsu)[OFF_RANGE + img * 2 + 1];
    float invbw = (float)NBINS / fmaxf(emax - emin, 1e-20f);
    float b2v = b2[0];
    const float* vimg = ws + OFF_V + img * NI * HID;   // wave-uniform
    __syncthreads();

    const float* ep = emb + (size_t)img * C * INTER + q;
    float u[HID];
    #pragma unroll
    for (int k = 0; k < HID; k++) u[k] = 0.f;
    #pragma unroll
    for (int c = 0; c < C; c++) {
        float ev = ep[c * INTER];
        #pragma unroll
        for (int k = 0; k < HID; k++) u[k] = fmaf(ev, W1[c * HID + k], u[k]);
    }
    int g = gt[img * INTER + q];
    for (int n = 0; n < NI; n++) {
        const float* vn = vimg + n * HID;
        float lg0 = b2v, lg1 = 0.f, lg2 = 0.f, lg3 = 0.f;
        #pragma unroll
        for (int k = 0; k < HID; k += 4) {
            lg0 = fmaf(fmaxf(vn[k + 0] - u[k + 0], 0.f), W2[k + 0], lg0);
            lg1 = fmaf(fmaxf(vn[k + 1] - u[k + 1], 0.f), W2[k + 1], lg1);
            lg2 = fmaf(fmaxf(vn[k + 2] - u[k + 2], 0.f), W2[k + 2], lg2);
            lg3 = fmaf(fmaxf(vn[k + 3] - u[k + 3], 0.f), W2[k + 3], lg3);
        }
        float lg = (lg0 + lg1) + (lg2 + lg3);
        bool pos = (g == n + 1);
        float err = pos ? (1.f - lg) : (1.f + lg);
        int bn = (int)((emax - err) * invbw);
        bn = bn < 0 ? 0 : (bn >= NBINS ? NBINS - 1 : bn);
        atomicAdd(&s_h[bn], pos ? 0x10001u : 1u);
    }
    __syncthreads();
    unsigned* gc = wsu + OFF_HCNT + (size_t)bx * NBINS;
    for (int i = tid; i < NBINS; i += THR) gc[i] = s_h[i];
}

// k_reduce: collapse the BPI partials per (img, bin). 32 blocks, coalesced.
__global__ void k_reduce(unsigned* wsu) {
    int tid = threadIdx.x, b = blockIdx.x;
    int img = b >> 3;
    int bn = (b & 7) * 256 + tid;             // 8 blocks/image * 256 = 2048
    unsigned cnt = 0, pos = 0;
    for (int r = 0; r < BPI; r++) {
        unsigned pk = wsu[OFF_HCNT + (size_t)(img * BPI + r) * NBINS + bn];
        cnt += pk & 0xFFFFu;
        pos += pk >> 16;
    }
    wsu[OFF_FCNT + img * NBINS + bn] = cnt;
    wsu[OFF_FPOS + img * NBINS + bn] = pos;
}

// k_loss: per-image (4 parallel blocks) -- bin-center sums, exact pad
// contributions, prefix scan, Lovasz loss in double, atomicAdd into out.
__global__ void k_loss(const float* ws, const unsigned* wsu, float* out) {
    const int T = 256, CHUNK = NBINS / T;     // 8
    int img = blockIdx.x, tid = threadIdx.x;
    __shared__ unsigned s_cnt[NBINS], s_pos[NBINS];  // 16 KB
    __shared__ float s_sum[NBINS];                   // 8 KB
    __shared__ unsigned s_pc[T], s_pp[T];
    __shared__ double s_a[T];
    float emin = ((const float*)wsu)[OFF_RANGE + img * 2];
    float emax = ((const float*)wsu)[OFF_RANGE + img * 2 + 1];
    float bw = (emax - emin) / (float)NBINS;
    float invbw = (float)NBINS / fmaxf(emax - emin, 1e-20f);
    for (int i = tid; i < NBINS; i += T) {
        unsigned cv = wsu[OFF_FCNT + img * NBINS + i];
        s_cnt[i] = cv;
        s_pos[i] = wsu[OFF_FPOS + img * NBINS + i];
        float center = emax - ((float)i + 0.5f) * bw;
        s_sum[i] = (float)cv * fmaxf(center, 0.f);
    }
    __syncthreads();
    // pad-region: exact error values, PADMULT each, label 0
    if (tid < NI) {
        float pe = ws[OFF_PERR + img * NI + tid];
        int bn = (int)((emax - pe) * invbw);
        bn = bn < 0 ? 0 : (bn >= NBINS ? NBINS - 1 : bn);
        atomicAdd(&s_cnt[bn], (unsigned)PADMULT);
        atomicAdd(&s_sum[bn], (float)PADMULT * fmaxf(pe, 0.f));
    }
    __syncthreads();
    unsigned ccnt = 0, cpos = 0;
    for (int j = 0; j < CHUNK; j++) {
        int bn = tid * CHUNK + j;
        ccnt += s_cnt[bn]; cpos += s_pos[bn];
    }
    s_pc[tid] = ccnt; s_pp[tid] = cpos;
    __syncthreads();
    for (int off = 1; off < T; off <<= 1) {
        unsigned ac = 0, ap = 0;
        if (tid >= off) { ac = s_pc[tid - off]; ap = s_pp[tid - off]; }
        __syncthreads();
        s_pc[tid] += ac; s_pp[tid] += ap;
        __syncthreads();
    }
    double Gd = (double)s_pp[T - 1];
    double r = (double)(s_pc[tid] - ccnt);
    double L = (double)(s_pp[tid] - cpos);
    double Jprev = 1.0 - (Gd - L) / (Gd + r - L);
    double acc = 0.0;
    for (int j = 0; j < CHUNK; j++) {
        int bn = tid * CHUNK + j;
        unsigned cv = s_cnt[bn], pv = s_pos[bn];
        if (cv) {
            r += (double)cv; L += (double)pv;
            double J = 1.0 - (Gd - L) / (Gd + r - L);
            double mean = (double)s_sum[bn] / (double)cv;
            acc += mean * (J - Jprev);
            Jprev = J;
        }
    }
    s_a[tid] = acc;
    __syncthreads();
    for (int s = T / 2; s > 0; s >>= 1) {
        if (tid < s) s_a[tid] += s_a[tid + s];
        __syncthreads();
    }
    if (tid == 0) atomicAdd(out, (float)(s_a[0] * 0.25));  // mean over B=4
}

extern "C" void kernel_launch(void* const* d_in, const int* in_sizes, int n_in,
                              void* d_out, int out_size, void* d_ws, size_t ws_size,
                              hipStream_t stream) {
    const float* emb = (const float*)d_in[0];
    const float* wgt = (const float*)d_in[1];
    const int*   gt  = (const int*)d_in[2];
    const float* W1  = (const float*)d_in[3];
    const float* b1  = (const float*)d_in[4];
    const float* W2  = (const float*)d_in[5];
    const float* b2  = (const float*)d_in[6];
    float* out = (float*)d_out;
    float* ws  = (float*)d_ws;
    unsigned* wsu = (unsigned*)d_ws;

    k_init<<<1, 256, 0, stream>>>(wsu, out);
    k_stats<<<NBLK, THR, 0, stream>>>(emb, wgt, gt, ws, wsu);
    k_centers<<<B, THR, 0, stream>>>(W1, b1, W2, b2, ws, wsu);
    k_hist<<<NBLK, THR, 0, stream>>>(emb, gt, W1, W2, b2, ws, wsu);
    k_reduce<<<32, 256, 0, stream>>>(wsu);
    k_loss<<<B, 256, 0, stream>>>(ws, wsu, out);
}

// Round 13
// 138.563 us; speedup vs baseline: 1.2691x; 1.0141x over previous
//
#include <hip/hip_runtime.h>

#define NBINS 2048
#define B 4
#define C 16
#define HID 32
#define NI 32
#define INTER 36864           // 192*192 interior pixels per image
#define PADMULT 28672         // 256*256 - 192*192 padded pixels per instance
#define EPSF 1e-6f
#define THR 256
#define BPI 144               // blocks per image, 1 pixel/thread
#define NBLK (B * BPI)        // 576 free-running blocks

// ---- ws layout (uint units)  [R10-winner layout, NBINS=2048]
#define OFF_COUNTS 0                      // [B][NI] float
#define OFF_CSUMS  (OFF_COUNTS + B*NI)    // [B][NI][C] float
#define OFF_V      (OFF_CSUMS + B*NI*C)   // [B][NI][HID] float
#define OFF_PERR   (OFF_V + B*NI*HID)     // [B][NI] float
#define OFF_MKEY   (OFF_PERR + B*NI)      // [B] uint: fmap(max ||e||^2)
#define OFF_RANGE  (OFF_MKEY + B)         // [B][2] float: emin, emax
#define CTRL_END   (OFF_RANGE + 2*B)
#define OFF_HCNT   8192                   // [NBLK][NBINS] packed cnt|pos<<16
#define OFF_FCNT   (OFF_HCNT + NBLK*NBINS)  // [B][NBINS]
#define OFF_FPOS   (OFF_FCNT + B*NBINS)     // [B][NBINS]

__device__ inline unsigned fmap(float f) {
    unsigned u = __float_as_uint(f);
    return (u & 0x80000000u) ? ~u : (u | 0x80000000u);
}
__device__ inline float funmap(unsigned k) {
    return (k & 0x80000000u) ? __uint_as_float(k & 0x7fffffffu)
                             : __uint_as_float(~k);
}

// Tiny init: zero control region + out. Kernel boundaries provide all
// inter-kernel visibility (no fences anywhere -- R9 lesson).
__global__ void k_init(unsigned* wsu, float* out) {
    int i = threadIdx.x;
    if (i < CTRL_END) wsu[i] = 0u;
    if (i == 0) out[0] = 0.f;
}

// k_stats: per-instance counts & weighted embedding sums + max ||e||^2.
// LDS-local accumulation, then device-scope global atomics (coherent).
__global__ __launch_bounds__(THR, 4) void k_stats(
        const float* __restrict__ emb, const float* __restrict__ wgt,
        const int* __restrict__ gt, float* ws, unsigned* wsu) {
    __shared__ float s_cnt[NI];
    __shared__ float s_sum[NI * 17];   // stride 17: avoid 2-bank aliasing
    __shared__ unsigned s_mk;
    int tid = threadIdx.x, bx = blockIdx.x;
    int img = bx / BPI;
    int q = (bx - img * BPI) * THR + tid;
    for (int i = tid; i < NI; i += THR) s_cnt[i] = 0.f;
    for (int i = tid; i < NI * 17; i += THR) s_sum[i] = 0.f;
    if (tid == 0) s_mk = 0u;
    __syncthreads();

    int g = gt[img * INTER + q];
    const float* ep = emb + (size_t)img * C * INTER + q;
    float e[C];
    float nrm = 0.f;
    #pragma unroll
    for (int c = 0; c < C; c++) { e[c] = ep[c * INTER]; nrm = fmaf(e[c], e[c], nrm); }
    if (g > 0) {
        float wv = wgt[img * INTER + q];
        atomicAdd(&s_cnt[g - 1], wv);
        #pragma unroll
        for (int c = 0; c < C; c++)
            atomicAdd(&s_sum[(g - 1) * 17 + c], e[c] * wv);
    }
    atomicMax(&s_mk, fmap(nrm));
    __syncthreads();
    for (int i = tid; i < NI; i += THR)
        atomicAdd(&ws[OFF_COUNTS + img * NI + i], s_cnt[i]);
    for (int i = tid; i < NI * C; i += THR) {
        int n = i / C, c = i - n * C;
        atomicAdd(&ws[OFF_CSUMS + (img * NI + n) * C + c], s_sum[n * 17 + c]);
    }
    if (tid == 0) atomicMax(&wsu[OFF_MKEY + img], s_mk);
}

// k_centers: one block per image. v[n,k] = centers.W1 + b1; pad errors
// (u=0 exactly); analytic histogram range via Cauchy-Schwarz:
// |u_k| <= max||e|| * ||W1_k|| => lg in [lo,hi] per instance.
__global__ void k_centers(const float* __restrict__ W1, const float* __restrict__ b1,
                          const float* __restrict__ W2, const float* __restrict__ b2,
                          float* ws, unsigned* wsu) {
    int im = blockIdx.x, tid = threadIdx.x;
    __shared__ float s_v[NI * HID];
    __shared__ float s_a[HID];
    __shared__ unsigned s_lo, s_hi;
    float b2v = b2[0];
    float M = sqrtf(funmap(wsu[OFF_MKEY + im]));
    if (tid < HID) {
        float ssq = 0.f;
        #pragma unroll
        for (int c = 0; c < C; c++)
            ssq = fmaf(W1[c * HID + tid], W1[c * HID + tid], ssq);
        s_a[tid] = M * sqrtf(ssq);
    }
    if (tid == 0) { s_lo = 0xFFFFFFFFu; s_hi = 0u; }
    for (int idx = tid; idx < NI * HID; idx += THR) {
        int n = idx >> 5, k = idx & 31;
        float cv = ws[OFF_COUNTS + im * NI + n] + EPSF;
        float acc = b1[k];
        #pragma unroll
        for (int c = 0; c < C; c++)
            acc += (ws[OFF_CSUMS + (im * NI + n) * C + c] / cv) * W1[c * HID + k];
        s_v[idx] = acc;
        ws[OFF_V + im * NI * HID + idx] = acc;
    }
    __syncthreads();
    if (tid < NI) {
        float lo = b2v, hi = b2v, lgp = b2v;
        #pragma unroll
        for (int k = 0; k < HID; k++) {
            float vk = s_v[tid * HID + k], a = s_a[k], w = W2[k];
            float thi = fmaxf(vk + a, 0.f), tlo = fmaxf(vk - a, 0.f);
            hi += w * (w > 0.f ? thi : tlo);
            lo += w * (w > 0.f ? tlo : thi);
            lgp = fmaf(fmaxf(vk, 0.f), w, lgp);   // pad pixels: u = 0 exact
        }
        float pe = 1.f + lgp;
        ws[OFF_PERR + im * NI + tid] = pe;
        atomicMin(&s_lo, fmap(fminf(1.f - hi, 1.f + lo)));
        atomicMax(&s_hi, fmap(fmaxf(1.f - lo, 1.f + hi)));
    }
    __syncthreads();
    if (tid == 0) {
        ((float*)wsu)[OFF_RANGE + im * 2]     = funmap(s_lo);
        ((float*)wsu)[OFF_RANGE + im * 2 + 1] = funmap(s_hi);
    }
}

// k_hist: LDS histogram per block (free-running), plain-store flush.
// v/W1/W2 via wave-uniform scalar loads; scalar fp32 inner loop.
// R13 change: n-loop unrolled 4x -- the per-instance s_load_dwordx16 of
// vn[] is ~200cyc L2 latency that a single-iteration loop exposes at
// 2.25 blocks/CU; unrolling batches 4 instances' scalar loads and
// overlaps them with the previous instances' FMA chains.
__global__ __launch_bounds__(THR, 4) void k_hist(
        const float* __restrict__ emb, const int* __restrict__ gt,
        const float* __restrict__ W1, const float* __restrict__ W2,
        const float* __restrict__ b2, const float* __restrict__ ws,
        unsigned* wsu) {
    __shared__ unsigned s_h[NBINS];   // 8 KB
    int tid = threadIdx.x, bx = blockIdx.x;
    int img = bx / BPI;
    int q = (bx - img * BPI) * THR + tid;
    for (int i = tid; i < NBINS; i += THR) s_h[i] = 0u;
    float emin = ((const float*)wsu)[OFF_RANGE + img * 2];
    float emax = ((const float*)wsu)[OFF_RANGE + img * 2 + 1];
    float invbw = (float)NBINS / fmaxf(emax - emin, 1e-20f);
    float b2v = b2[0];
    const float* vimg = ws + OFF_V + img * NI * HID;   // wave-uniform
    __syncthreads();

    const float* ep = emb + (size_t)img * C * INTER + q;
    float u[HID];
    #pragma unroll
    for (int k = 0; k < HID; k++) u[k] = 0.f;
    #pragma unroll
    for (int c = 0; c < C; c++) {
        float ev = ep[c * INTER];
        #pragma unroll
        for (int k = 0; k < HID; k++) u[k] = fmaf(ev, W1[c * HID + k], u[k]);
    }
    int g = gt[img * INTER + q];
    #pragma unroll 4
    for (int n = 0; n < NI; n++) {
        const float* vn = vimg + n * HID;
        float lg0 = b2v, lg1 = 0.f, lg2 = 0.f, lg3 = 0.f;
        #pragma unroll
        for (int k = 0; k < HID; k += 4) {
            lg0 = fmaf(fmaxf(vn[k + 0] - u[k + 0], 0.f), W2[k + 0], lg0);
            lg1 = fmaf(fmaxf(vn[k + 1] - u[k + 1], 0.f), W2[k + 1], lg1);
            lg2 = fmaf(fmaxf(vn[k + 2] - u[k + 2], 0.f), W2[k + 2], lg2);
            lg3 = fmaf(fmaxf(vn[k + 3] - u[k + 3], 0.f), W2[k + 3], lg3);
        }
        float lg = (lg0 + lg1) + (lg2 + lg3);
        bool pos = (g == n + 1);
        float err = pos ? (1.f - lg) : (1.f + lg);
        int bn = (int)((emax - err) * invbw);
        bn = bn < 0 ? 0 : (bn >= NBINS ? NBINS - 1 : bn);
        atomicAdd(&s_h[bn], pos ? 0x10001u : 1u);
    }
    __syncthreads();
    unsigned* gc = wsu + OFF_HCNT + (size_t)bx * NBINS;
    for (int i = tid; i < NBINS; i += THR) gc[i] = s_h[i];
}

// k_reduce: collapse the BPI partials per (img, bin). 32 blocks, coalesced.
__global__ void k_reduce(unsigned* wsu) {
    int tid = threadIdx.x, b = blockIdx.x;
    int img = b >> 3;
    int bn = (b & 7) * 256 + tid;             // 8 blocks/image * 256 = 2048
    unsigned cnt = 0, pos = 0;
    for (int r = 0; r < BPI; r++) {
        unsigned pk = wsu[OFF_HCNT + (size_t)(img * BPI + r) * NBINS + bn];
        cnt += pk & 0xFFFFu;
        pos += pk >> 16;
    }
    wsu[OFF_FCNT + img * NBINS + bn] = cnt;
    wsu[OFF_FPOS + img * NBINS + bn] = pos;
}

// k_loss: per-image (4 parallel blocks) -- bin-center sums, exact pad
// contributions, prefix scan, Lovasz loss in double, atomicAdd into out.
__global__ void k_loss(const float* ws, const unsigned* wsu, float* out) {
    const int T = 256, CHUNK = NBINS / T;     // 8
    int img = blockIdx.x, tid = threadIdx.x;
    __shared__ unsigned s_cnt[NBINS], s_pos[NBINS];  // 16 KB
    __shared__ float s_sum[NBINS];                   // 8 KB
    __shared__ unsigned s_pc[T], s_pp[T];
    __shared__ double s_a[T];
    float emin = ((const float*)wsu)[OFF_RANGE + img * 2];
    float emax = ((const float*)wsu)[OFF_RANGE + img * 2 + 1];
    float bw = (emax - emin) / (float)NBINS;
    float invbw = (float)NBINS / fmaxf(emax - emin, 1e-20f);
    for (int i = tid; i < NBINS; i += T) {
        unsigned cv = wsu[OFF_FCNT + img * NBINS + i];
        s_cnt[i] = cv;
        s_pos[i] = wsu[OFF_FPOS + img * NBINS + i];
        float center = emax - ((float)i + 0.5f) * bw;
        s_sum[i] = (float)cv * fmaxf(center, 0.f);
    }
    __syncthreads();
    // pad-region: exact error values, PADMULT each, label 0
    if (tid < NI) {
        float pe = ws[OFF_PERR + img * NI + tid];
        int bn = (int)((emax - pe) * invbw);
        bn = bn < 0 ? 0 : (bn >= NBINS ? NBINS - 1 : bn);
        atomicAdd(&s_cnt[bn], (unsigned)PADMULT);
        atomicAdd(&s_sum[bn], (float)PADMULT * fmaxf(pe, 0.f));
    }
    __syncthreads();
    unsigned ccnt = 0, cpos = 0;
    for (int j = 0; j < CHUNK; j++) {
        int bn = tid * CHUNK + j;
        ccnt += s_cnt[bn]; cpos += s_pos[bn];
    }
    s_pc[tid] = ccnt; s_pp[tid] = cpos;
    __syncthreads();
    for (int off = 1; off < T; off <<= 1) {
        unsigned ac = 0, ap = 0;
        if (tid >= off) { ac = s_pc[tid - off]; ap = s_pp[tid - off]; }
        __syncthreads();
        s_pc[tid] += ac; s_pp[tid] += ap;
        __syncthreads();
    }
    double Gd = (double)s_pp[T - 1];
    double r = (double)(s_pc[tid] - ccnt);
    double L = (double)(s_pp[tid] - cpos);
    double Jprev = 1.0 - (Gd - L) / (Gd + r - L);
    double acc = 0.0;
    for (int j = 0; j < CHUNK; j++) {
        int bn = tid * CHUNK + j;
        unsigned cv = s_cnt[bn], pv = s_pos[bn];
        if (cv) {
            r += (double)cv; L += (double)pv;
            double J = 1.0 - (Gd - L) / (Gd + r - L);
            double mean = (double)s_sum[bn] / (double)cv;
            acc += mean * (J - Jprev);
            Jprev = J;
        }
    }
    s_a[tid] = acc;
    __syncthreads();
    for (int s = T / 2; s > 0; s >>= 1) {
        if (tid < s) s_a[tid] += s_a[tid + s];
        __syncthreads();
    }
    if (tid == 0) atomicAdd(out, (float)(s_a[0] * 0.25));  // mean over B=4
}

extern "C" void kernel_launch(void* const* d_in, const int* in_sizes, int n_in,
                              void* d_out, int out_size, void* d_ws, size_t ws_size,
                              hipStream_t stream) {
    const float* emb = (const float*)d_in[0];
    const float* wgt = (const float*)d_in[1];
    const int*   gt  = (const int*)d_in[2];
    const float* W1  = (const float*)d_in[3];
    const float* b1  = (const float*)d_in[4];
    const float* W2  = (const float*)d_in[5];
    const float* b2  = (const float*)d_in[6];
    float* out = (float*)d_out;
    float* ws  = (float*)d_ws;
    unsigned* wsu = (unsigned*)d_ws;

    k_init<<<1, 256, 0, stream>>>(wsu, out);
    k_stats<<<NBLK, THR, 0, stream>>>(emb, wgt, gt, ws, wsu);
    k_centers<<<B, THR, 0, stream>>>(W1, b1, W2, b2, ws, wsu);
    k_hist<<<NBLK, THR, 0, stream>>>(emb, gt, W1, W2, b2, ws, wsu);
    k_reduce<<<32, 256, 0, stream>>>(wsu);
    k_loss<<<B, 256, 0, stream>>>(ws, wsu, out);
}